// Round 1
// baseline (70.831 us; speedup 1.0000x reference)
//
#include <hip/hip_runtime.h>

// Ball query: for each of NQ=32768 query points g (p_grid), find the first
// K=10 indices i (ascending) of x (N2=8192 points) with
//   d2 = (|g|^2 + |x_i|^2) - 2*dot(g, x_i) <= 0.25^2
// Output (concat, float32): mapping [NQ,K] (index as float, 0 if unfound),
//                           points  [NQ,K,3] (x_i coords, 0 if unfound).
//
// R4: same one-wave-per-query scan as R3 (70.9 us), but:
//  - candidate loads packed: each lane owns 4 consecutive points loaded as
//    3x global_load_dwordx4 (was 12 scalar dwords per 256-candidate chunk)
//  - d2 evaluated pairwise in f32x2 ext-vectors -> v_pk_mul/add_f32 on
//    gfx950 (contract(off) keeps the exact unfused left-to-right rounding
//    that matched the reference bit-for-bit in R3)
//  - 128-thread blocks (2 waves) for finer retirement granularity
// Index layout per chunk is now base + 4*lane + j; rank = found +
// popc(m_j & lanes_below) summed over j, plus own-lane prefix in j order.
// Same first-K-ascending set as R3 -> identical output bits.

#define BQ_K   10
#define BQ_N2  8192
#define BQ_NQ  32768
#define BQ_R2  0.0625f

typedef float f32x2 __attribute__((ext_vector_type(2)));

__global__ __launch_bounds__(128) void bq_kernel(
    const float4* __restrict__ x4,    // x viewed as float4[N2*3/4]
    const float* __restrict__ pg,     // [NQ,3]
    float* __restrict__ map_out,      // [NQ,K]
    float* __restrict__ pts_out)      // [NQ,K,3]
{
#pragma clang fp contract(off)
    const int lane = threadIdx.x & 63;
    const int q = (int)blockIdx.x * 2 + (threadIdx.x >> 6);   // wave per query

    const float gx = pg[q * 3 + 0];
    const float gy = pg[q * 3 + 1];
    const float gz = pg[q * 3 + 2];
    const float gg = (gx * gx + gy * gy) + gz * gz;   // contract off: exact

    float* __restrict__ mo = map_out + (size_t)q * BQ_K;
    float* __restrict__ po = pts_out + (size_t)q * BQ_K * 3;
    const unsigned long long lt = (1ull << lane) - 1ull;   // lanes below me

    // Prime: lane owns points [4*lane, 4*lane+3] of chunk 0 -> 3 float4 loads.
    float4 f0, f1, f2;
    {
        const int i4 = lane * 3;          // ((0>>2)+lane)*3
        f0 = x4[i4]; f1 = x4[i4 + 1]; f2 = x4[i4 + 2];
    }

    int found = 0;   // wave-uniform count of valid points seen so far

    for (int base = 0; base < BQ_N2; base += 256) {
        // Prefetch next 256 candidates (3 dwordx4 per lane).
        float4 n0, n1, n2;
        const bool more = (base + 256) < BQ_N2;
        if (more) {
            const int i4 = (((base + 256) >> 2) + lane) * 3;
            n0 = x4[i4]; n1 = x4[i4 + 1]; n2 = x4[i4 + 2];
        }

        // Unpack 4 consecutive points from the 3 float4 registers.
        const float x0 = f0.x, y0 = f0.y, z0 = f0.z;
        const float x1 = f0.w, y1 = f1.x, z1 = f1.y;
        const float x2 = f1.z, y2 = f1.w, z2 = f2.x;
        const float x3 = f2.y, y3 = f2.z, z3 = f2.w;

        // Pairwise packed d2: same per-element rounding/association as the
        // reference ((x*x+y*y)+z*z, (gx*x+gy*y)+gz*z, (gg+xx)-2*dot).
        const f32x2 XA = {x0, x1}, YA = {y0, y1}, ZA = {z0, z1};
        const f32x2 XB = {x2, x3}, YB = {y2, y3}, ZB = {z2, z3};
        const f32x2 xxA = (XA * XA + YA * YA) + ZA * ZA;
        const f32x2 dtA = (gx * XA + gy * YA) + gz * ZA;
        const f32x2 d2A = (gg + xxA) - 2.0f * dtA;
        const f32x2 xxB = (XB * XB + YB * YB) + ZB * ZB;
        const f32x2 dtB = (gx * XB + gy * YB) + gz * ZB;
        const f32x2 d2B = (gg + xxB) - 2.0f * dtB;

        const bool v0 = d2A.x <= BQ_R2;
        const bool v1 = d2A.y <= BQ_R2;
        const bool v2 = d2B.x <= BQ_R2;
        const bool v3 = d2B.y <= BQ_R2;
        const unsigned long long m0 = __ballot(v0);
        const unsigned long long m1 = __ballot(v1);
        const unsigned long long m2 = __ballot(v2);
        const unsigned long long m3 = __ballot(v3);

        if ((m0 | m1 | m2 | m3) != 0ull) {
            // Candidates at lanes strictly below me have smaller indices for
            // ALL j (idx = base + 4*lane + j); own-lane prefix is j-ordered.
            int slot = found + __popcll(m0 & lt) + __popcll(m1 & lt)
                             + __popcll(m2 & lt) + __popcll(m3 & lt);
            const int idx0 = base + lane * 4;
            if (v0) {
                if (slot < BQ_K) {
                    mo[slot] = (float)(idx0 + 0);
                    po[slot * 3 + 0] = x0; po[slot * 3 + 1] = y0; po[slot * 3 + 2] = z0;
                }
                ++slot;
            }
            if (v1) {
                if (slot < BQ_K) {
                    mo[slot] = (float)(idx0 + 1);
                    po[slot * 3 + 0] = x1; po[slot * 3 + 1] = y1; po[slot * 3 + 2] = z1;
                }
                ++slot;
            }
            if (v2) {
                if (slot < BQ_K) {
                    mo[slot] = (float)(idx0 + 2);
                    po[slot * 3 + 0] = x2; po[slot * 3 + 1] = y2; po[slot * 3 + 2] = z2;
                }
                ++slot;
            }
            if (v3) {
                if (slot < BQ_K) {
                    mo[slot] = (float)(idx0 + 3);
                    po[slot * 3 + 0] = x3; po[slot * 3 + 1] = y3; po[slot * 3 + 2] = z3;
                }
                ++slot;
            }
            found += __popcll(m0) + __popcll(m1) + __popcll(m2) + __popcll(m3);
            if (found >= BQ_K) break;                 // uniform early exit
        }

        if (more) { f0 = n0; f1 = n1; f2 = n2; }
    }

    // Zero-fill unfound slots (d_out is poisoned 0xAA before every launch).
    const int filled = found < BQ_K ? found : BQ_K;
    if (lane < BQ_K && lane >= filled) {
        mo[lane] = 0.0f;
        po[lane * 3 + 0] = 0.0f;
        po[lane * 3 + 1] = 0.0f;
        po[lane * 3 + 2] = 0.0f;
    }
}

extern "C" void kernel_launch(void* const* d_in, const int* in_sizes, int n_in,
                              void* d_out, int out_size, void* d_ws, size_t ws_size,
                              hipStream_t stream) {
    const float* x  = (const float*)d_in[0];   // (1, 8192, 3) float32
    const float* pg = (const float*)d_in[1];   // (1, 64, 32, 16, 3) float32
    float* out = (float*)d_out;
    float* map_out = out;                          // [NQ*K]
    float* pts_out = out + (size_t)BQ_NQ * BQ_K;   // [NQ*K*3]

    // One wave per query: 32768 queries / 2 waves per 128-thread block.
    bq_kernel<<<BQ_NQ / 2, 128, 0, stream>>>((const float4*)x, pg, map_out, pts_out);
}